// Round 1
// baseline (111.709 us; speedup 1.0000x reference)
//
#include <hip/hip_runtime.h>

#define BB 512
#define LL 4096
#define MAXLAG 20
#define NLAGS 41
#define TAU 0.05f

__global__ void zero_out_kernel(float* out) {
    if (threadIdx.x < 4) out[threadIdx.x] = 0.0f;
}

__global__ __launch_bounds__(256) void lagloss_kernel(const float* __restrict__ pred,
                                                      const float* __restrict__ gt,
                                                      float* __restrict__ out) {
    __shared__ float sp_[LL];
    __shared__ float sg_[LL];
    __shared__ float red[4][6];
    __shared__ float pcc_s[NLAGS];
    __shared__ float l1_s[NLAGS];

    const int b = blockIdx.x;
    const int tid = threadIdx.x;
    const float* __restrict__ prow = pred + (size_t)b * LL;
    const float* __restrict__ grow = gt + (size_t)b * LL;

    // stage both rows in LDS (vectorized: 16B/lane)
    for (int i = tid; i < LL / 4; i += 256) {
        ((float4*)sp_)[i] = ((const float4*)prow)[i];
        ((float4*)sg_)[i] = ((const float4*)grow)[i];
    }
    __syncthreads();

    const int wid = tid >> 6;
    const int lane = tid & 63;

    for (int il = 0; il < NLAGS; ++il) {
        const int lag = il - MAXLAG;
        const int offp = lag > 0 ? lag : 0;
        const int offg = lag < 0 ? -lag : 0;
        const int n = LL - (lag < 0 ? -lag : lag);

        float sp = 0.f, sg = 0.f, spg = 0.f, spp = 0.f, sgg = 0.f, sab = 0.f;
        for (int i = tid; i < n; i += 256) {
            const float p = sp_[i + offp];
            const float g = sg_[i + offg];
            sp += p;
            sg += g;
            spg = fmaf(p, g, spg);
            spp = fmaf(p, p, spp);
            sgg = fmaf(g, g, sgg);
            sab += fabsf(p - g);
        }
        // wave-level butterfly reduce (width 64)
        for (int d = 32; d; d >>= 1) {
            sp  += __shfl_down(sp, d, 64);
            sg  += __shfl_down(sg, d, 64);
            spg += __shfl_down(spg, d, 64);
            spp += __shfl_down(spp, d, 64);
            sgg += __shfl_down(sgg, d, 64);
            sab += __shfl_down(sab, d, 64);
        }
        if (lane == 0) {
            red[wid][0] = sp;  red[wid][1] = sg;  red[wid][2] = spg;
            red[wid][3] = spp; red[wid][4] = sgg; red[wid][5] = sab;
        }
        __syncthreads();
        if (tid == 0) {
            float t[6];
            #pragma unroll
            for (int k = 0; k < 6; ++k)
                t[k] = red[0][k] + red[1][k] + red[2][k] + red[3][k];
            const float fn = (float)n;
            const float num  = t[2] - t[0] * t[1] / fn;
            const float varp = t[3] - t[0] * t[0] / fn;
            const float varg = t[4] - t[1] * t[1] / fn;
            const float den2 = fmaxf(varp * varg, 1e-12f);
            pcc_s[il] = num / sqrtf(den2);
            l1_s[il]  = t[5] / fn;
        }
        __syncthreads();  // also protects red[] reuse next iteration
    }

    if (tid == 0) {
        // argmax (first occurrence on ties, matching jnp.argmax)
        float best = pcc_s[0];
        int bi = 0;
        #pragma unroll
        for (int i = 1; i < NLAGS; ++i) {
            if (pcc_s[i] > best) { best = pcc_s[i]; bi = i; }
        }
        const float zero_pcc = pcc_s[MAXLAG];

        // softmax(pcc/TAU) weighted |lag|/MAXLAG
        float wsum = 0.f, psum = 0.f;
        #pragma unroll
        for (int i = 0; i < NLAGS; ++i) {
            const float w = expf((pcc_s[i] - best) / TAU);
            wsum += w;
            const int lagi = i - MAXLAG;
            const float lc = (float)(lagi < 0 ? -lagi : lagi) / (float)MAXLAG;
            psum += w * lc;
        }
        const float pen = psum / wsum;

        const float inv = 1.0f / (float)BB;
        atomicAdd(&out[0], (1.0f - best) * inv);
        atomicAdd(&out[1], l1_s[bi] * inv);
        atomicAdd(&out[2], (1.0f - zero_pcc) * inv);
        atomicAdd(&out[3], pen * inv);
    }
}

extern "C" void kernel_launch(void* const* d_in, const int* in_sizes, int n_in,
                              void* d_out, int out_size, void* d_ws, size_t ws_size,
                              hipStream_t stream) {
    const float* pred = (const float*)d_in[0];
    const float* gt   = (const float*)d_in[1];
    float* out = (float*)d_out;

    zero_out_kernel<<<1, 64, 0, stream>>>(out);
    lagloss_kernel<<<BB, 256, 0, stream>>>(pred, gt, out);
}

// Round 2
// 57.496 us; speedup vs baseline: 1.9429x; 1.9429x over previous
//
#include <hip/hip_runtime.h>
#include <math.h>

#define BB 512
#define LL 4096
#define MAXLAG 20
#define NLAGS 41
#define TAU 0.05f
#define CHUNK 16
#define PADF 24   // zero pad floats on each side of the p buffer

__global__ void zero_out_kernel(float* out) {
    if (threadIdx.x < 4) out[threadIdx.x] = 0.0f;
}

__global__ __launch_bounds__(256) void lagloss_kernel(const float* __restrict__ pred,
                                                      const float* __restrict__ gt,
                                                      float* __restrict__ out) {
    __shared__ float spbuf[PADF + LL + PADF];
    __shared__ float sg_[LL];
    __shared__ float redPG[4][NLAGS];
    __shared__ float redAB[4][NLAGS];
    __shared__ float edges[10][MAXLAG + 1];  // 0:prefP 1:prefPP 2:prefG 3:prefGG 4:prefAG
                                             // 5:sufP  6:sufPP  7:sufG  8:sufGG  9:sufAG
    __shared__ float wsums[4][4];            // per-wave Sp,Sg,Spp,Sgg
    __shared__ float pcc_s[NLAGS];
    __shared__ float l1_s[NLAGS];

    float* sp_ = spbuf + PADF;
    const int b = blockIdx.x;
    const int tid = threadIdx.x;
    const int wid = tid >> 6;
    const int lane = tid & 63;
    const float* __restrict__ prow = pred + (size_t)b * LL;
    const float* __restrict__ grow = gt + (size_t)b * LL;

    // zero the pads (so register windows read 0 outside [0,LL))
    if (tid < PADF) { spbuf[tid] = 0.0f; spbuf[PADF + LL + tid] = 0.0f; }

    // ---- stage rows to LDS (coalesced float4) + accumulate full-row sums ----
    float ap = 0.f, ag = 0.f, app = 0.f, agg = 0.f;
    #pragma unroll
    for (int it = 0; it < (LL / 4) / 256; ++it) {
        const int i = tid + it * 256;
        const float4 p4 = ((const float4*)prow)[i];
        const float4 g4 = ((const float4*)grow)[i];
        ((float4*)sp_)[i] = p4;
        ((float4*)sg_)[i] = g4;
        ap += p4.x + p4.y + p4.z + p4.w;
        ag += g4.x + g4.y + g4.z + g4.w;
        app = fmaf(p4.x, p4.x, fmaf(p4.y, p4.y, fmaf(p4.z, p4.z, fmaf(p4.w, p4.w, app))));
        agg = fmaf(g4.x, g4.x, fmaf(g4.y, g4.y, fmaf(g4.z, g4.z, fmaf(g4.w, g4.w, agg))));
    }
    #pragma unroll
    for (int d = 32; d; d >>= 1) {
        ap  += __shfl_down(ap, d, 64);
        ag  += __shfl_down(ag, d, 64);
        app += __shfl_down(app, d, 64);
        agg += __shfl_down(agg, d, 64);
    }
    if (lane == 0) {
        wsums[wid][0] = ap; wsums[wid][1] = ag;
        wsums[wid][2] = app; wsums[wid][3] = agg;
    }
    __syncthreads();

    // ---- edge prefix/suffix sums: 210 threads, one (array, k) pair each ----
    if (tid < 10 * (MAXLAG + 1)) {
        const int a = tid / (MAXLAG + 1);
        const int k = tid % (MAXLAG + 1);
        float s = 0.f;
        for (int i = 0; i < k; ++i) {
            float x;
            switch (a) {
                case 0: x = sp_[i]; break;
                case 1: x = sp_[i] * sp_[i]; break;
                case 2: x = sg_[i]; break;
                case 3: x = sg_[i] * sg_[i]; break;
                case 4: x = fabsf(sg_[i]); break;
                case 5: x = sp_[LL - 1 - i]; break;
                case 6: x = sp_[LL - 1 - i] * sp_[LL - 1 - i]; break;
                case 7: x = sg_[LL - 1 - i]; break;
                case 8: x = sg_[LL - 1 - i] * sg_[LL - 1 - i]; break;
                default: x = fabsf(sg_[LL - 1 - i]); break;
            }
            s += x;
        }
        edges[a][k] = s;
    }

    // ---- load register windows (all compile-time indexed -> stays in VGPRs) ----
    const int c0 = tid * CHUNK;
    float pr[CHUNK + 2 * MAXLAG + 4];  // [c0-20 .. c0+35], 56 floats
    #pragma unroll
    for (int k = 0; k < 14; ++k) {
        const float4 v = *(const float4*)&sp_[c0 - MAXLAG + 4 * k];
        pr[4 * k] = v.x; pr[4 * k + 1] = v.y; pr[4 * k + 2] = v.z; pr[4 * k + 3] = v.w;
    }
    float gr[CHUNK];
    #pragma unroll
    for (int k = 0; k < 4; ++k) {
        const float4 v = *(const float4*)&sg_[c0 + 4 * k];
        gr[4 * k] = v.x; gr[4 * k + 1] = v.y; gr[4 * k + 2] = v.z; gr[4 * k + 3] = v.w;
    }

    // ---- lag loop: pure register math, per-wave reduction, no barriers ----
    #pragma unroll
    for (int il = 0; il < NLAGS; ++il) {
        const int l = il - MAXLAG;
        float s0 = 0.f, s1 = 0.f, a0 = 0.f, a1 = 0.f;
        #pragma unroll
        for (int k = 0; k < CHUNK; k += 2) {
            const float p0 = pr[MAXLAG + l + k];
            const float p1 = pr[MAXLAG + l + k + 1];
            const float g0 = gr[k];
            const float g1 = gr[k + 1];
            s0 = fmaf(p0, g0, s0);
            s1 = fmaf(p1, g1, s1);
            a0 += fabsf(p0 - g0);
            a1 += fabsf(p1 - g1);
        }
        float spg = s0 + s1;
        float sab = a0 + a1;
        #pragma unroll
        for (int d = 32; d; d >>= 1) {
            spg += __shfl_down(spg, d, 64);
            sab += __shfl_down(sab, d, 64);
        }
        if (lane == 0) { redPG[wid][il] = spg; redAB[wid][il] = sab; }
    }
    __syncthreads();

    // ---- per-lag assembly: 41 threads, one lag each ----
    if (tid < NLAGS) {
        const int il = tid;
        const int l = il - MAXLAG;
        const int m = l < 0 ? -l : l;
        const float fn = (float)(LL - m);
        float spg = redPG[0][il] + redPG[1][il] + redPG[2][il] + redPG[3][il];
        float sab = redAB[0][il] + redAB[1][il] + redAB[2][il] + redAB[3][il];
        const float Sp  = wsums[0][0] + wsums[1][0] + wsums[2][0] + wsums[3][0];
        const float Sg  = wsums[0][1] + wsums[1][1] + wsums[2][1] + wsums[3][1];
        const float Spp = wsums[0][2] + wsums[1][2] + wsums[2][2] + wsums[3][2];
        const float Sgg = wsums[0][3] + wsums[1][3] + wsums[2][3] + wsums[3][3];
        float Spw, Sgw, Sppw, Sggw;
        if (l >= 0) {
            Spw  = Sp  - edges[0][m];
            Sppw = Spp - edges[1][m];
            Sgw  = Sg  - edges[7][m];
            Sggw = Sgg - edges[8][m];
            sab -= edges[9][m];
        } else {
            Spw  = Sp  - edges[5][m];
            Sppw = Spp - edges[6][m];
            Sgw  = Sg  - edges[2][m];
            Sggw = Sgg - edges[3][m];
            sab -= edges[4][m];
        }
        const float num  = spg - Spw * Sgw / fn;
        const float varp = Sppw - Spw * Spw / fn;
        const float varg = Sggw - Sgw * Sgw / fn;
        const float den2 = fmaxf(varp * varg, 1e-12f);
        pcc_s[il] = num / sqrtf(den2);
        l1_s[il]  = sab / fn;
    }
    __syncthreads();

    // ---- final scalars ----
    if (tid == 0) {
        float best = pcc_s[0];
        int bi = 0;
        #pragma unroll
        for (int i = 1; i < NLAGS; ++i) {
            if (pcc_s[i] > best) { best = pcc_s[i]; bi = i; }
        }
        const float zero_pcc = pcc_s[MAXLAG];
        float wsum = 0.f, psum = 0.f;
        #pragma unroll
        for (int i = 0; i < NLAGS; ++i) {
            const float w = __expf((pcc_s[i] - best) / TAU);
            wsum += w;
            const int lagi = i - MAXLAG;
            const float lc = (float)(lagi < 0 ? -lagi : lagi) / (float)MAXLAG;
            psum = fmaf(w, lc, psum);
        }
        const float pen = psum / wsum;
        const float inv = 1.0f / (float)BB;
        atomicAdd(&out[0], (1.0f - best) * inv);
        atomicAdd(&out[1], l1_s[bi] * inv);
        atomicAdd(&out[2], (1.0f - zero_pcc) * inv);
        atomicAdd(&out[3], pen * inv);
    }
}

extern "C" void kernel_launch(void* const* d_in, const int* in_sizes, int n_in,
                              void* d_out, int out_size, void* d_ws, size_t ws_size,
                              hipStream_t stream) {
    const float* pred = (const float*)d_in[0];
    const float* gt   = (const float*)d_in[1];
    float* out = (float*)d_out;

    zero_out_kernel<<<1, 64, 0, stream>>>(out);
    lagloss_kernel<<<BB, 256, 0, stream>>>(pred, gt, out);
}

// Round 3
// 49.164 us; speedup vs baseline: 2.2722x; 1.1695x over previous
//
#include <hip/hip_runtime.h>
#include <math.h>

#define BB 512
#define LL 4096
#define MAXLAG 20
#define NLAGS 41
#define TAU 0.05f
#define CHUNK 16
#define PRW (CHUNK + 2 * MAXLAG + 4)   // 56: window [c0-20 .. c0+35]

__global__ void zero_out_kernel(float* out) {
    if (threadIdx.x < 4) out[threadIdx.x] = 0.0f;
}

// ---- canonical GCN/CDNA full-wave (64-lane) sum via DPP; result lands in lane 63 ----
template<int CTRL, int RM, int BM, bool BC>
__device__ __forceinline__ float dpp_add(float x) {
    const int t = __builtin_amdgcn_update_dpp(0, __float_as_int(x), CTRL, RM, BM, BC);
    return x + __int_as_float(t);
}
__device__ __forceinline__ float wave_sum63(float x) {
    x = dpp_add<0x111, 0xf, 0xf, true >(x);  // row_shr:1
    x = dpp_add<0x112, 0xf, 0xf, true >(x);  // row_shr:2
    x = dpp_add<0x114, 0xf, 0xf, true >(x);  // row_shr:4
    x = dpp_add<0x118, 0xf, 0xf, true >(x);  // row_shr:8  -> lane15 of each row = row sum
    x = dpp_add<0x142, 0xa, 0xf, false>(x);  // row_bcast:15 -> rows 1,3
    x = dpp_add<0x143, 0xc, 0xf, false>(x);  // row_bcast:31 -> rows 2,3; lane63 = total
    return x;
}

struct SmemT {
    float redPG[4][NLAGS];
    float redAB[4][NLAGS];
    float edges[10][MAXLAG + 1];  // 0:prefP 1:prefPP 2:prefG 3:prefGG 4:prefAG
                                  // 5:sufP  6:sufPP  7:sufG  8:sufGG  9:sufAG
    float wsums[4][4];
    float pcc_s[NLAGS];
    float l1_s[NLAGS];
};

// ---- compile-time-guaranteed unroll of the 41 lag steps: all pr[] indices constant ----
template<int IL>
struct LagChain {
    static __device__ __forceinline__ void run(const float (&pr)[PRW], const float (&gr)[CHUNK],
                                               SmemT& sm, int wid, int lane) {
        float s0 = 0.f, s1 = 0.f, a0 = 0.f, a1 = 0.f;
        #pragma unroll
        for (int k = 0; k < CHUNK; k += 2) {
            const float p0 = pr[IL + k];      // pr index: MAXLAG + (IL-MAXLAG) + k = IL + k
            const float p1 = pr[IL + k + 1];
            const float g0 = gr[k];
            const float g1 = gr[k + 1];
            s0 = fmaf(p0, g0, s0);
            s1 = fmaf(p1, g1, s1);
            a0 += fabsf(p0 - g0);
            a1 += fabsf(p1 - g1);
        }
        const float spg = wave_sum63(s0 + s1);
        const float sab = wave_sum63(a0 + a1);
        if (lane == 63) { sm.redPG[wid][IL] = spg; sm.redAB[wid][IL] = sab; }
        LagChain<IL + 1>::run(pr, gr, sm, wid, lane);
    }
};
template<>
struct LagChain<NLAGS> {
    static __device__ __forceinline__ void run(const float (&)[PRW], const float (&)[CHUNK],
                                               SmemT&, int, int) {}
};

__global__ __launch_bounds__(256) void lagloss_kernel(const float* __restrict__ pred,
                                                      const float* __restrict__ gt,
                                                      float* __restrict__ out) {
    __shared__ SmemT sm;

    const int b = blockIdx.x;
    const int tid = threadIdx.x;
    const int wid = tid >> 6;
    const int lane = tid & 63;
    const float* __restrict__ prow = pred + (size_t)b * LL;
    const float* __restrict__ grow = gt + (size_t)b * LL;

    // ---- per-thread register windows, straight from global (L1/L2 absorbs overlap) ----
    const int c0 = tid * CHUNK;
    float pr[PRW];
    #pragma unroll
    for (int k = 0; k < PRW / 4; ++k) {
        const int off = c0 - MAXLAG + 4 * k;
        const int offc = off < 0 ? 0 : (off > LL - 4 ? LL - 4 : off);
        const float4 v = *(const float4*)&prow[offc];
        const bool ok = (off >= 0) && (off <= LL - 4);  // each float4 fully in or fully out
        pr[4 * k + 0] = ok ? v.x : 0.f;
        pr[4 * k + 1] = ok ? v.y : 0.f;
        pr[4 * k + 2] = ok ? v.z : 0.f;
        pr[4 * k + 3] = ok ? v.w : 0.f;
    }
    float gr[CHUNK];
    #pragma unroll
    for (int k = 0; k < CHUNK / 4; ++k) {
        const float4 v = *(const float4*)&grow[c0 + 4 * k];
        gr[4 * k] = v.x; gr[4 * k + 1] = v.y; gr[4 * k + 2] = v.z; gr[4 * k + 3] = v.w;
    }

    // ---- full-row sums from own chunk (pr[20..35] == p[c0..c0+15]) ----
    {
        float ap = 0.f, ag = 0.f, app = 0.f, agg = 0.f;
        #pragma unroll
        for (int k = 0; k < CHUNK; ++k) {
            const float p = pr[MAXLAG + k];
            const float g = gr[k];
            ap += p; ag += g;
            app = fmaf(p, p, app);
            agg = fmaf(g, g, agg);
        }
        ap = wave_sum63(ap); ag = wave_sum63(ag);
        app = wave_sum63(app); agg = wave_sum63(agg);
        if (lane == 63) {
            sm.wsums[wid][0] = ap; sm.wsums[wid][1] = ag;
            sm.wsums[wid][2] = app; sm.wsums[wid][3] = agg;
        }
    }

    // ---- edge prefix/suffix sums (210 threads, one (array,k) pair each; global reads) ----
    if (tid < 10 * (MAXLAG + 1)) {
        const int a = tid / (MAXLAG + 1);
        const int k = tid % (MAXLAG + 1);
        float s = 0.f;
        for (int i = 0; i < k; ++i) {
            float x;
            switch (a) {
                case 0: x = prow[i]; break;
                case 1: x = prow[i] * prow[i]; break;
                case 2: x = grow[i]; break;
                case 3: x = grow[i] * grow[i]; break;
                case 4: x = fabsf(grow[i]); break;
                case 5: x = prow[LL - 1 - i]; break;
                case 6: x = prow[LL - 1 - i] * prow[LL - 1 - i]; break;
                case 7: x = grow[LL - 1 - i]; break;
                case 8: x = grow[LL - 1 - i] * grow[LL - 1 - i]; break;
                default: x = fabsf(grow[LL - 1 - i]); break;
            }
            s += x;
        }
        sm.edges[a][k] = s;
    }

    // ---- 41 lag steps: pure register math + DPP reduces, no barriers ----
    LagChain<0>::run(pr, gr, sm, wid, lane);
    __syncthreads();

    // ---- per-lag assembly: 41 threads, one lag each ----
    if (tid < NLAGS) {
        const int il = tid;
        const int l = il - MAXLAG;
        const int m = l < 0 ? -l : l;
        const float fn = (float)(LL - m);
        float spg = sm.redPG[0][il] + sm.redPG[1][il] + sm.redPG[2][il] + sm.redPG[3][il];
        float sab = sm.redAB[0][il] + sm.redAB[1][il] + sm.redAB[2][il] + sm.redAB[3][il];
        const float Sp  = sm.wsums[0][0] + sm.wsums[1][0] + sm.wsums[2][0] + sm.wsums[3][0];
        const float Sg  = sm.wsums[0][1] + sm.wsums[1][1] + sm.wsums[2][1] + sm.wsums[3][1];
        const float Spp = sm.wsums[0][2] + sm.wsums[1][2] + sm.wsums[2][2] + sm.wsums[3][2];
        const float Sgg = sm.wsums[0][3] + sm.wsums[1][3] + sm.wsums[2][3] + sm.wsums[3][3];
        float Spw, Sgw, Sppw, Sggw;
        if (l >= 0) {
            Spw  = Sp  - sm.edges[0][m];
            Sppw = Spp - sm.edges[1][m];
            Sgw  = Sg  - sm.edges[7][m];
            Sggw = Sgg - sm.edges[8][m];
            sab -= sm.edges[9][m];
        } else {
            Spw  = Sp  - sm.edges[5][m];
            Sppw = Spp - sm.edges[6][m];
            Sgw  = Sg  - sm.edges[2][m];
            Sggw = Sgg - sm.edges[3][m];
            sab -= sm.edges[4][m];
        }
        const float num  = spg - Spw * Sgw / fn;
        const float varp = Sppw - Spw * Spw / fn;
        const float varg = Sggw - Sgw * Sgw / fn;
        const float den2 = fmaxf(varp * varg, 1e-12f);
        sm.pcc_s[il] = num / sqrtf(den2);
        sm.l1_s[il]  = sab / fn;
    }
    __syncthreads();

    // ---- final scalars ----
    if (tid == 0) {
        float best = sm.pcc_s[0];
        int bi = 0;
        #pragma unroll
        for (int i = 1; i < NLAGS; ++i) {
            if (sm.pcc_s[i] > best) { best = sm.pcc_s[i]; bi = i; }
        }
        const float zero_pcc = sm.pcc_s[MAXLAG];
        float wsum = 0.f, psum = 0.f;
        #pragma unroll
        for (int i = 0; i < NLAGS; ++i) {
            const float w = __expf((sm.pcc_s[i] - best) / TAU);
            wsum += w;
            const int lagi = i - MAXLAG;
            const float lc = (float)(lagi < 0 ? -lagi : lagi) / (float)MAXLAG;
            psum = fmaf(w, lc, psum);
        }
        const float pen = psum / wsum;
        const float inv = 1.0f / (float)BB;
        atomicAdd(&out[0], (1.0f - best) * inv);
        atomicAdd(&out[1], sm.l1_s[bi] * inv);
        atomicAdd(&out[2], (1.0f - zero_pcc) * inv);
        atomicAdd(&out[3], pen * inv);
    }
}

extern "C" void kernel_launch(void* const* d_in, const int* in_sizes, int n_in,
                              void* d_out, int out_size, void* d_ws, size_t ws_size,
                              hipStream_t stream) {
    const float* pred = (const float*)d_in[0];
    const float* gt   = (const float*)d_in[1];
    float* out = (float*)d_out;

    zero_out_kernel<<<1, 64, 0, stream>>>(out);
    lagloss_kernel<<<BB, 256, 0, stream>>>(pred, gt, out);
}

// Round 4
// 48.998 us; speedup vs baseline: 2.2799x; 1.0034x over previous
//
#include <hip/hip_runtime.h>
#include <math.h>

#define BB 512
#define LL 4096
#define MAXLAG 20
#define NLAGS 41
#define TAU 0.05f
#define CHUNK 16

// Padded LDS layout: signal index i (may be negative into the zero pad) maps to
// i' = i + 32, float-index fi = i' + 4*(i'/16)  (i.e. 16 B pad every 64 B).
// Window reads at lane stride 80 B -> 8 lanes cover all 32 banks -> conflict-free.
// Buffer: i' in [0, 4160) -> fi < 5200.

__global__ void zero_out_kernel(float* out) {
    if (threadIdx.x < 4) out[threadIdx.x] = 0.0f;
}

// ---- 64-lane sum via DPP; result in lane 63 ----
template<int CTRL, int RM, int BM, bool BC>
__device__ __forceinline__ float dpp_add(float x) {
    const int t = __builtin_amdgcn_update_dpp(0, __float_as_int(x), CTRL, RM, BM, BC);
    return x + __int_as_float(t);
}
__device__ __forceinline__ float wave_sum63(float x) {
    x = dpp_add<0x111, 0xf, 0xf, true >(x);  // row_shr:1
    x = dpp_add<0x112, 0xf, 0xf, true >(x);  // row_shr:2
    x = dpp_add<0x114, 0xf, 0xf, true >(x);  // row_shr:4
    x = dpp_add<0x118, 0xf, 0xf, true >(x);  // row_shr:8
    x = dpp_add<0x142, 0xa, 0xf, false>(x);  // row_bcast:15
    x = dpp_add<0x143, 0xc, 0xf, false>(x);  // row_bcast:31 -> lane63 total
    return x;
}

struct SmemT {
    float redPG[4][NLAGS];
    float redAB[4][NLAGS];
    float edges[10][MAXLAG + 1];  // 0:prefP 1:prefPP 2:prefG 3:prefGG 4:prefAG
                                  // 5:sufP  6:sufPP  7:sufG  8:sufGG  9:sufAG
    float wsums[4][4];
    float pcc_s[NLAGS];
    float l1_s[NLAGS];
};

// one lag group: lags L0 .. L0+G-1 (L0 % 4 == 0 for 16B-aligned window start)
template<int L0, int G>
__device__ __forceinline__ void lag_group(const float* __restrict__ lds_p,
                                          const float (&gr)[CHUNK],
                                          SmemT& sm, int tid, int wid, int lane) {
    constexpr int NW4 = (G + CHUNK + 2) / 4;   // float4 loads; G=8 -> 6, G=1 -> 4
    float pw[NW4 * 4];
    const int pbase = 20 * tid;                // 80 B per thread (padded layout)
    #pragma unroll
    for (int k = 0; k < NW4; ++k) {
        const int v = L0 + 32 + 4 * k;         // compile-time after unroll
        const int fo = v + 4 * (v / 16);
        const float4 w = *(const float4*)&lds_p[pbase + fo];
        pw[4 * k + 0] = w.x; pw[4 * k + 1] = w.y;
        pw[4 * k + 2] = w.z; pw[4 * k + 3] = w.w;
    }
    #pragma unroll
    for (int dl = 0; dl < G; ++dl) {
        float s0 = 0.f, s1 = 0.f, a0 = 0.f, a1 = 0.f;
        #pragma unroll
        for (int k = 0; k < CHUNK; k += 2) {
            const float p0 = pw[dl + k];
            const float p1 = pw[dl + k + 1];
            const float g0 = gr[k];
            const float g1 = gr[k + 1];
            s0 = fmaf(p0, g0, s0);
            s1 = fmaf(p1, g1, s1);
            a0 += fabsf(p0 - g0);
            a1 += fabsf(p1 - g1);
        }
        const float spg = wave_sum63(s0 + s1);
        const float sab = wave_sum63(a0 + a1);
        const int il = L0 + MAXLAG + dl;
        if (lane == 63) { sm.redPG[wid][il] = spg; sm.redAB[wid][il] = sab; }
    }
}

__global__ __launch_bounds__(256, 2) void lagloss_kernel(const float* __restrict__ pred,
                                                         const float* __restrict__ gt,
                                                         float* __restrict__ out) {
    __shared__ float lds_p[5200];
    __shared__ float lds_g[5200];
    __shared__ SmemT sm;

    const int b = blockIdx.x;
    const int tid = threadIdx.x;
    const int wid = tid >> 6;
    const int lane = tid & 63;
    const float* __restrict__ prow = pred + (size_t)b * LL;
    const float* __restrict__ grow = gt + (size_t)b * LL;

    // ---- zero the pads: i' in [0,32) and [4128,4160), as 8 float4 each side ----
    if (tid < 32) {
        const int m = tid & 15;          // 0..7 low pad, 8..15 high pad
        const int mm = m & 7;
        const int fi = (m < 8 ? 0 : 5160) + 4 * mm + 4 * (mm >> 2);
        float* buf = (tid < 16) ? lds_p : lds_g;
        *(float4*)&buf[fi] = float4{0.f, 0.f, 0.f, 0.f};
    }

    // ---- stage rows into padded LDS (coalesced global float4) + full-row sums ----
    const int wb = 4 * tid + 4 * ((tid + 8) >> 2) + 32;
    float ap = 0.f, ag = 0.f, app = 0.f, agg = 0.f;
    #pragma unroll
    for (int it = 0; it < 4; ++it) {
        const int j = tid + 256 * it;        // float4 index in row
        const float4 p4 = ((const float4*)prow)[j];
        const float4 g4 = ((const float4*)grow)[j];
        *(float4*)&lds_p[wb + 1280 * it] = p4;
        *(float4*)&lds_g[wb + 1280 * it] = g4;
        ap += p4.x + p4.y + p4.z + p4.w;
        ag += g4.x + g4.y + g4.z + g4.w;
        app = fmaf(p4.x, p4.x, fmaf(p4.y, p4.y, fmaf(p4.z, p4.z, fmaf(p4.w, p4.w, app))));
        agg = fmaf(g4.x, g4.x, fmaf(g4.y, g4.y, fmaf(g4.z, g4.z, fmaf(g4.w, g4.w, agg))));
    }
    ap = wave_sum63(ap); ag = wave_sum63(ag);
    app = wave_sum63(app); agg = wave_sum63(agg);
    if (lane == 63) {
        sm.wsums[wid][0] = ap; sm.wsums[wid][1] = ag;
        sm.wsums[wid][2] = app; sm.wsums[wid][3] = agg;
    }

    // ---- edge prefix/suffix sums (210 threads; global reads are L1-warm) ----
    if (tid < 10 * (MAXLAG + 1)) {
        const int a = tid / (MAXLAG + 1);
        const int k = tid % (MAXLAG + 1);
        float s = 0.f;
        for (int i = 0; i < k; ++i) {
            float x;
            switch (a) {
                case 0: x = prow[i]; break;
                case 1: x = prow[i] * prow[i]; break;
                case 2: x = grow[i]; break;
                case 3: x = grow[i] * grow[i]; break;
                case 4: x = fabsf(grow[i]); break;
                case 5: x = prow[LL - 1 - i]; break;
                case 6: x = prow[LL - 1 - i] * prow[LL - 1 - i]; break;
                case 7: x = grow[LL - 1 - i]; break;
                case 8: x = grow[LL - 1 - i] * grow[LL - 1 - i]; break;
                default: x = fabsf(grow[LL - 1 - i]); break;
            }
            s += x;
        }
        sm.edges[a][k] = s;
    }
    __syncthreads();

    // ---- g chunk into registers (conflict-free padded b128 reads) ----
    float gr[CHUNK];
    {
        const int gbase = 20 * tid;
        #pragma unroll
        for (int k = 0; k < CHUNK / 4; ++k) {
            const int v = 32 + 4 * k;
            const int fo = v + 4 * (v / 16);
            const float4 w = *(const float4*)&lds_g[gbase + fo];
            gr[4 * k + 0] = w.x; gr[4 * k + 1] = w.y;
            gr[4 * k + 2] = w.z; gr[4 * k + 3] = w.w;
        }
    }

    // ---- 41 lags in groups: small live window, pure-register inner math ----
    lag_group<-20, 8>(lds_p, gr, sm, tid, wid, lane);
    lag_group<-12, 8>(lds_p, gr, sm, tid, wid, lane);
    lag_group< -4, 8>(lds_p, gr, sm, tid, wid, lane);
    lag_group<  4, 8>(lds_p, gr, sm, tid, wid, lane);
    lag_group< 12, 8>(lds_p, gr, sm, tid, wid, lane);
    lag_group< 20, 1>(lds_p, gr, sm, tid, wid, lane);
    __syncthreads();

    // ---- per-lag assembly: 41 threads, one lag each ----
    if (tid < NLAGS) {
        const int il = tid;
        const int l = il - MAXLAG;
        const int m = l < 0 ? -l : l;
        const float fn = (float)(LL - m);
        float spg = sm.redPG[0][il] + sm.redPG[1][il] + sm.redPG[2][il] + sm.redPG[3][il];
        float sab = sm.redAB[0][il] + sm.redAB[1][il] + sm.redAB[2][il] + sm.redAB[3][il];
        const float Sp  = sm.wsums[0][0] + sm.wsums[1][0] + sm.wsums[2][0] + sm.wsums[3][0];
        const float Sg  = sm.wsums[0][1] + sm.wsums[1][1] + sm.wsums[2][1] + sm.wsums[3][1];
        const float Spp = sm.wsums[0][2] + sm.wsums[1][2] + sm.wsums[2][2] + sm.wsums[3][2];
        const float Sgg = sm.wsums[0][3] + sm.wsums[1][3] + sm.wsums[2][3] + sm.wsums[3][3];
        float Spw, Sgw, Sppw, Sggw;
        if (l >= 0) {
            Spw  = Sp  - sm.edges[0][m];
            Sppw = Spp - sm.edges[1][m];
            Sgw  = Sg  - sm.edges[7][m];
            Sggw = Sgg - sm.edges[8][m];
            sab -= sm.edges[9][m];
        } else {
            Spw  = Sp  - sm.edges[5][m];
            Sppw = Spp - sm.edges[6][m];
            Sgw  = Sg  - sm.edges[2][m];
            Sggw = Sgg - sm.edges[3][m];
            sab -= sm.edges[4][m];
        }
        const float num  = spg - Spw * Sgw / fn;
        const float varp = Sppw - Spw * Spw / fn;
        const float varg = Sggw - Sgw * Sgw / fn;
        const float den2 = fmaxf(varp * varg, 1e-12f);
        sm.pcc_s[il] = num / sqrtf(den2);
        sm.l1_s[il]  = sab / fn;
    }
    __syncthreads();

    // ---- final scalars ----
    if (tid == 0) {
        float best = sm.pcc_s[0];
        int bi = 0;
        #pragma unroll
        for (int i = 1; i < NLAGS; ++i) {
            if (sm.pcc_s[i] > best) { best = sm.pcc_s[i]; bi = i; }
        }
        const float zero_pcc = sm.pcc_s[MAXLAG];
        float wsum = 0.f, psum = 0.f;
        #pragma unroll
        for (int i = 0; i < NLAGS; ++i) {
            const float w = __expf((sm.pcc_s[i] - best) / TAU);
            wsum += w;
            const int lagi = i - MAXLAG;
            const float lc = (float)(lagi < 0 ? -lagi : lagi) / (float)MAXLAG;
            psum = fmaf(w, lc, psum);
        }
        const float pen = psum / wsum;
        const float inv = 1.0f / (float)BB;
        atomicAdd(&out[0], (1.0f - best) * inv);
        atomicAdd(&out[1], sm.l1_s[bi] * inv);
        atomicAdd(&out[2], (1.0f - zero_pcc) * inv);
        atomicAdd(&out[3], pen * inv);
    }
}

extern "C" void kernel_launch(void* const* d_in, const int* in_sizes, int n_in,
                              void* d_out, int out_size, void* d_ws, size_t ws_size,
                              hipStream_t stream) {
    const float* pred = (const float*)d_in[0];
    const float* gt   = (const float*)d_in[1];
    float* out = (float*)d_out;

    zero_out_kernel<<<1, 64, 0, stream>>>(out);
    lagloss_kernel<<<BB, 256, 0, stream>>>(pred, gt, out);
}

// Round 5
// 22.469 us; speedup vs baseline: 4.9717x; 2.1807x over previous
//
#include <hip/hip_runtime.h>
#include <math.h>

#define BB 512
#define LL 4096
#define MAXLAG 20
#define NLAGS 41
#define TAU 0.05f
#define CHUNK 16

// Padded LDS layout: signal index i (may be negative into the zero pad) maps to
// i' = i + 32, float-index fi = i' + 4*(i'/16)  (16 B pad every 64 B).

__device__ __forceinline__ int pad_idx(int i) {
    const int ip = i + 32;
    return ip + 4 * (ip >> 4);
}

// ---- 64-lane sum via DPP; result in lane 63 ----
template<int CTRL, int RM, int BM, bool BC>
__device__ __forceinline__ float dpp_add(float x) {
    const int t = __builtin_amdgcn_update_dpp(0, __float_as_int(x), CTRL, RM, BM, BC);
    return x + __int_as_float(t);
}
__device__ __forceinline__ float wave_sum63(float x) {
    x = dpp_add<0x111, 0xf, 0xf, true >(x);  // row_shr:1
    x = dpp_add<0x112, 0xf, 0xf, true >(x);  // row_shr:2
    x = dpp_add<0x114, 0xf, 0xf, true >(x);  // row_shr:4
    x = dpp_add<0x118, 0xf, 0xf, true >(x);  // row_shr:8
    x = dpp_add<0x142, 0xa, 0xf, false>(x);  // row_bcast:15
    x = dpp_add<0x143, 0xc, 0xf, false>(x);  // row_bcast:31 -> lane63 total
    return x;
}

struct SmemT {
    float redPG[4][NLAGS];
    float redAB[4][NLAGS];
    float edges[10][MAXLAG + 1];  // 0:prefP 1:prefPP 2:prefG 3:prefGG 4:prefAG
                                  // 5:sufP  6:sufPP  7:sufG  8:sufGG  9:sufAG
    float wsums[4][4];
    float pcc_s[NLAGS];
    float l1_s[NLAGS];
};

// one lag group: lags L0 .. L0+G-1 (L0 % 4 == 0 for 16B-aligned window start)
template<int L0, int G>
__device__ __forceinline__ void lag_group(const float* __restrict__ lds_p,
                                          const float (&gr)[CHUNK],
                                          SmemT& sm, int tid, int wid, int lane) {
    constexpr int NW4 = (G + CHUNK + 2) / 4;   // float4 loads; G=8 -> 6, G=1 -> 4
    float pw[NW4 * 4];
    const int pbase = 20 * tid;                // 80 B per thread (padded layout)
    #pragma unroll
    for (int k = 0; k < NW4; ++k) {
        const int v = L0 + 32 + 4 * k;         // compile-time after unroll
        const int fo = v + 4 * (v / 16);
        const float4 w = *(const float4*)&lds_p[pbase + fo];
        pw[4 * k + 0] = w.x; pw[4 * k + 1] = w.y;
        pw[4 * k + 2] = w.z; pw[4 * k + 3] = w.w;
    }
    #pragma unroll
    for (int dl = 0; dl < G; ++dl) {
        float s0 = 0.f, s1 = 0.f, a0 = 0.f, a1 = 0.f;
        #pragma unroll
        for (int k = 0; k < CHUNK; k += 2) {
            const float p0 = pw[dl + k];
            const float p1 = pw[dl + k + 1];
            const float g0 = gr[k];
            const float g1 = gr[k + 1];
            s0 = fmaf(p0, g0, s0);
            s1 = fmaf(p1, g1, s1);
            a0 += fabsf(p0 - g0);
            a1 += fabsf(p1 - g1);
        }
        const float spg = wave_sum63(s0 + s1);
        const float sab = wave_sum63(a0 + a1);
        const int il = L0 + MAXLAG + dl;
        if (lane == 63) { sm.redPG[wid][il] = spg; sm.redAB[wid][il] = sab; }
    }
}

__global__ __launch_bounds__(256, 2) void lagloss_kernel(const float* __restrict__ pred,
                                                         const float* __restrict__ gt,
                                                         float4* __restrict__ ws) {
    __shared__ float lds_p[5200];
    __shared__ float lds_g[5200];
    __shared__ SmemT sm;

    const int b = blockIdx.x;
    const int tid = threadIdx.x;
    const int wid = tid >> 6;
    const int lane = tid & 63;
    const float* __restrict__ prow = pred + (size_t)b * LL;
    const float* __restrict__ grow = gt + (size_t)b * LL;

    // ---- zero the pads: i' in [0,32) and [4128,4160), as 8 float4 each side ----
    if (tid < 32) {
        const int m = tid & 15;          // 0..7 low pad, 8..15 high pad
        const int mm = m & 7;
        const int fi = (m < 8 ? 0 : 5160) + 4 * mm + 4 * (mm >> 2);
        float* buf = (tid < 16) ? lds_p : lds_g;
        *(float4*)&buf[fi] = float4{0.f, 0.f, 0.f, 0.f};
    }

    // ---- stage rows into padded LDS (coalesced global float4) + full-row sums ----
    const int wb = 4 * tid + 4 * ((tid + 8) >> 2) + 32;
    float ap = 0.f, ag = 0.f, app = 0.f, agg = 0.f;
    #pragma unroll
    for (int it = 0; it < 4; ++it) {
        const int j = tid + 256 * it;        // float4 index in row
        const float4 p4 = ((const float4*)prow)[j];
        const float4 g4 = ((const float4*)grow)[j];
        *(float4*)&lds_p[wb + 1280 * it] = p4;
        *(float4*)&lds_g[wb + 1280 * it] = g4;
        ap += p4.x + p4.y + p4.z + p4.w;
        ag += g4.x + g4.y + g4.z + g4.w;
        app = fmaf(p4.x, p4.x, fmaf(p4.y, p4.y, fmaf(p4.z, p4.z, fmaf(p4.w, p4.w, app))));
        agg = fmaf(g4.x, g4.x, fmaf(g4.y, g4.y, fmaf(g4.z, g4.z, fmaf(g4.w, g4.w, agg))));
    }
    ap = wave_sum63(ap); ag = wave_sum63(ag);
    app = wave_sum63(app); agg = wave_sum63(agg);
    if (lane == 63) {
        sm.wsums[wid][0] = ap; sm.wsums[wid][1] = ag;
        sm.wsums[wid][2] = app; sm.wsums[wid][3] = agg;
    }
    __syncthreads();

    // ---- edge prefix/suffix sums from LDS: 3 lanes per wave, 1 array each ----
    // a = 3*wid + lane:  buf = (a%5>=2) ? g : p;  dir = (a>=5);  op: a%5 -> 1,3=sq 4=abs
    {
        const int a = 3 * wid + lane;
        if (lane < 3 && a < 10) {
            const int m = a % 5;
            const bool useG = (m >= 2);
            const bool bwd = (a >= 5);
            const bool opSq = (m == 1 || m == 3);
            const bool opAbs = (m == 4);
            const float* buf = useG ? lds_g : lds_p;
            float s = 0.f;
            #pragma unroll
            for (int k = 0; k <= MAXLAG; ++k) {
                sm.edges[a][k] = s;
                if (k < MAXLAG) {
                    const int i = bwd ? (LL - 1 - k) : k;
                    const float x = buf[pad_idx(i)];
                    const float y = opSq ? x * x : (opAbs ? fabsf(x) : x);
                    s += y;
                }
            }
        }
    }

    // ---- g chunk into registers (padded b128 reads) ----
    float gr[CHUNK];
    {
        const int gbase = 20 * tid;
        #pragma unroll
        for (int k = 0; k < CHUNK / 4; ++k) {
            const int v = 32 + 4 * k;
            const int fo = v + 4 * (v / 16);
            const float4 w = *(const float4*)&lds_g[gbase + fo];
            gr[4 * k + 0] = w.x; gr[4 * k + 1] = w.y;
            gr[4 * k + 2] = w.z; gr[4 * k + 3] = w.w;
        }
    }

    // ---- 41 lags in groups: small live window, pure-register inner math ----
    lag_group<-20, 8>(lds_p, gr, sm, tid, wid, lane);
    lag_group<-12, 8>(lds_p, gr, sm, tid, wid, lane);
    lag_group< -4, 8>(lds_p, gr, sm, tid, wid, lane);
    lag_group<  4, 8>(lds_p, gr, sm, tid, wid, lane);
    lag_group< 12, 8>(lds_p, gr, sm, tid, wid, lane);
    lag_group< 20, 1>(lds_p, gr, sm, tid, wid, lane);
    __syncthreads();

    // ---- per-lag assembly: 41 threads, one lag each ----
    if (tid < NLAGS) {
        const int il = tid;
        const int l = il - MAXLAG;
        const int m = l < 0 ? -l : l;
        const float fn = (float)(LL - m);
        float spg = sm.redPG[0][il] + sm.redPG[1][il] + sm.redPG[2][il] + sm.redPG[3][il];
        float sab = sm.redAB[0][il] + sm.redAB[1][il] + sm.redAB[2][il] + sm.redAB[3][il];
        const float Sp  = sm.wsums[0][0] + sm.wsums[1][0] + sm.wsums[2][0] + sm.wsums[3][0];
        const float Sg  = sm.wsums[0][1] + sm.wsums[1][1] + sm.wsums[2][1] + sm.wsums[3][1];
        const float Spp = sm.wsums[0][2] + sm.wsums[1][2] + sm.wsums[2][2] + sm.wsums[3][2];
        const float Sgg = sm.wsums[0][3] + sm.wsums[1][3] + sm.wsums[2][3] + sm.wsums[3][3];
        float Spw, Sgw, Sppw, Sggw;
        if (l >= 0) {
            Spw  = Sp  - sm.edges[0][m];
            Sppw = Spp - sm.edges[1][m];
            Sgw  = Sg  - sm.edges[7][m];
            Sggw = Sgg - sm.edges[8][m];
            sab -= sm.edges[9][m];
        } else {
            Spw  = Sp  - sm.edges[5][m];
            Sppw = Spp - sm.edges[6][m];
            Sgw  = Sg  - sm.edges[2][m];
            Sggw = Sgg - sm.edges[3][m];
            sab -= sm.edges[4][m];
        }
        const float num  = spg - Spw * Sgw / fn;
        const float varp = Sppw - Spw * Spw / fn;
        const float varg = Sggw - Sgw * Sgw / fn;
        const float den2 = fmaxf(varp * varg, 1e-12f);
        sm.pcc_s[il] = num / sqrtf(den2);
        sm.l1_s[il]  = sab / fn;
    }
    __syncthreads();

    // ---- per-block scalars -> plain float4 store to workspace (no atomics) ----
    if (tid == 0) {
        float best = sm.pcc_s[0];
        int bi = 0;
        #pragma unroll
        for (int i = 1; i < NLAGS; ++i) {
            if (sm.pcc_s[i] > best) { best = sm.pcc_s[i]; bi = i; }
        }
        const float zero_pcc = sm.pcc_s[MAXLAG];
        float wsum = 0.f, psum = 0.f;
        #pragma unroll
        for (int i = 0; i < NLAGS; ++i) {
            const float w = __expf((sm.pcc_s[i] - best) / TAU);
            wsum += w;
            const int lagi = i - MAXLAG;
            const float lc = (float)(lagi < 0 ? -lagi : lagi) / (float)MAXLAG;
            psum = fmaf(w, lc, psum);
        }
        const float pen = psum / wsum;
        ws[b] = float4{1.0f - best, sm.l1_s[bi], 1.0f - zero_pcc, pen};
    }
}

// ---- stage 2: reduce 512 float4 partials -> 4 output scalars ----
__global__ __launch_bounds__(512) void reduce_kernel(const float4* __restrict__ ws,
                                                     float* __restrict__ out) {
    __shared__ float4 part[8];
    const int tid = threadIdx.x;
    const int wid = tid >> 6;
    const int lane = tid & 63;
    const float4 v = ws[tid];
    const float x = wave_sum63(v.x);
    const float y = wave_sum63(v.y);
    const float z = wave_sum63(v.z);
    const float w = wave_sum63(v.w);
    if (lane == 63) part[wid] = float4{x, y, z, w};
    __syncthreads();
    if (tid == 0) {
        float s0 = 0.f, s1 = 0.f, s2 = 0.f, s3 = 0.f;
        #pragma unroll
        for (int i = 0; i < 8; ++i) {
            s0 += part[i].x; s1 += part[i].y; s2 += part[i].z; s3 += part[i].w;
        }
        const float inv = 1.0f / (float)BB;
        out[0] = s0 * inv;
        out[1] = s1 * inv;
        out[2] = s2 * inv;
        out[3] = s3 * inv;
    }
}

extern "C" void kernel_launch(void* const* d_in, const int* in_sizes, int n_in,
                              void* d_out, int out_size, void* d_ws, size_t ws_size,
                              hipStream_t stream) {
    const float* pred = (const float*)d_in[0];
    const float* gt   = (const float*)d_in[1];
    float* out = (float*)d_out;
    float4* ws = (float4*)d_ws;

    lagloss_kernel<<<BB, 256, 0, stream>>>(pred, gt, ws);
    reduce_kernel<<<1, 512, 0, stream>>>(ws, out);
}

// Round 6
// 18.342 us; speedup vs baseline: 6.0905x; 1.2250x over previous
//
#include <hip/hip_runtime.h>
#include <math.h>

#define BB 512
#define LL 4096
#define MAXLAG 20
#define NLAGS 41
#define TAU 0.05f
#define CHUNK 16

// Padded LDS layout: signal index i (may be negative into the zero pad) maps to
// i' = i + 32, float-index fi = i' + 4*(i'/16)  (16 B pad every 64 B).
__device__ __forceinline__ int pad_idx(int i) {
    const int ip = i + 32;
    return ip + 4 * (ip >> 4);
}

// ---- DPP adds ----
template<int CTRL, int RM, int BM, bool BC>
__device__ __forceinline__ float dpp_add(float x) {
    const int t = __builtin_amdgcn_update_dpp(0, __float_as_int(x), CTRL, RM, BM, BC);
    return x + __int_as_float(t);
}
// full 64-lane sum; result in lane 63
__device__ __forceinline__ float wave_sum63(float x) {
    x = dpp_add<0x111, 0xf, 0xf, true >(x);  // row_shr:1
    x = dpp_add<0x112, 0xf, 0xf, true >(x);  // row_shr:2
    x = dpp_add<0x114, 0xf, 0xf, true >(x);  // row_shr:4
    x = dpp_add<0x118, 0xf, 0xf, true >(x);  // row_shr:8
    x = dpp_add<0x142, 0xa, 0xf, false>(x);  // row_bcast:15
    x = dpp_add<0x143, 0xc, 0xf, false>(x);  // row_bcast:31 -> lane63 total
    return x;
}
// 16-lane row sum; result in lane 15 of each row
__device__ __forceinline__ float row_sum15(float x) {
    x = dpp_add<0x111, 0xf, 0xf, true >(x);
    x = dpp_add<0x112, 0xf, 0xf, true >(x);
    x = dpp_add<0x114, 0xf, 0xf, true >(x);
    x = dpp_add<0x118, 0xf, 0xf, true >(x);
    return x;
}

struct SmemT {
    float redPG[16][NLAGS];       // 16 row-partials per lag
    float edges[10][MAXLAG + 1];  // 0:prefP 1:prefPP 2:prefG 3:prefGG (4 unused)
                                  // 5:sufP  6:sufPP  7:sufG  8:sufGG  (9 unused)
    float wsums[4][4];
    float pcc_s[NLAGS];
    float l1part[16];
    float best_pcc, zero_pcc, pen;
    int best_il;
};

// one lag group: lags L0 .. L0+G-1 (L0 % 4 == 0 for 16B-aligned window start)
// computes ONLY spg (L1 deferred to the single best lag)
template<int L0, int G>
__device__ __forceinline__ void lag_group(const float* __restrict__ lds_p,
                                          const float (&gr)[CHUNK],
                                          SmemT& sm, int tid) {
    constexpr int NW4 = (G + CHUNK + 2) / 4;   // G=8 -> 6 float4, G=1 -> 4
    float pw[NW4 * 4];
    const int pbase = 20 * tid;                // 80 B per thread (padded layout)
    #pragma unroll
    for (int k = 0; k < NW4; ++k) {
        const int v = L0 + 32 + 4 * k;         // compile-time after unroll
        const int fo = v + 4 * (v / 16);
        const float4 w = *(const float4*)&lds_p[pbase + fo];
        pw[4 * k + 0] = w.x; pw[4 * k + 1] = w.y;
        pw[4 * k + 2] = w.z; pw[4 * k + 3] = w.w;
    }
    #pragma unroll
    for (int dl = 0; dl < G; ++dl) {
        float s0 = 0.f, s1 = 0.f;
        #pragma unroll
        for (int k = 0; k < CHUNK; k += 2) {
            s0 = fmaf(pw[dl + k],     gr[k],     s0);
            s1 = fmaf(pw[dl + k + 1], gr[k + 1], s1);
        }
        const float spg = row_sum15(s0 + s1);
        const int il = L0 + MAXLAG + dl;
        if ((tid & 15) == 15) sm.redPG[tid >> 4][il] = spg;
    }
}

__global__ __launch_bounds__(256, 2) void lagloss_kernel(const float* __restrict__ pred,
                                                         const float* __restrict__ gt,
                                                         float4* __restrict__ ws) {
    __shared__ float lds_p[5200];
    __shared__ float lds_g[5200];
    __shared__ SmemT sm;

    const int b = blockIdx.x;
    const int tid = threadIdx.x;
    const int wid = tid >> 6;
    const int lane = tid & 63;
    const float* __restrict__ prow = pred + (size_t)b * LL;
    const float* __restrict__ grow = gt + (size_t)b * LL;

    // ---- zero the pads: i' in [0,32) and [4128,4160), as 8 float4 each side ----
    if (tid < 32) {
        const int m = tid & 15;          // 0..7 low pad, 8..15 high pad
        const int mm = m & 7;
        const int fi = (m < 8 ? 0 : 5160) + 4 * mm + 4 * (mm >> 2);
        float* buf = (tid < 16) ? lds_p : lds_g;
        *(float4*)&buf[fi] = float4{0.f, 0.f, 0.f, 0.f};
    }

    // ---- stage rows into padded LDS (coalesced global float4) + full-row sums ----
    const int wb = 4 * tid + 4 * ((tid + 8) >> 2) + 32;
    float ap = 0.f, ag = 0.f, app = 0.f, agg = 0.f;
    #pragma unroll
    for (int it = 0; it < 4; ++it) {
        const int j = tid + 256 * it;        // float4 index in row
        const float4 p4 = ((const float4*)prow)[j];
        const float4 g4 = ((const float4*)grow)[j];
        *(float4*)&lds_p[wb + 1280 * it] = p4;
        *(float4*)&lds_g[wb + 1280 * it] = g4;
        ap += p4.x + p4.y + p4.z + p4.w;
        ag += g4.x + g4.y + g4.z + g4.w;
        app = fmaf(p4.x, p4.x, fmaf(p4.y, p4.y, fmaf(p4.z, p4.z, fmaf(p4.w, p4.w, app))));
        agg = fmaf(g4.x, g4.x, fmaf(g4.y, g4.y, fmaf(g4.z, g4.z, fmaf(g4.w, g4.w, agg))));
    }
    ap = wave_sum63(ap); ag = wave_sum63(ag);
    app = wave_sum63(app); agg = wave_sum63(agg);
    if (lane == 63) {
        sm.wsums[wid][0] = ap; sm.wsums[wid][1] = ag;
        sm.wsums[wid][2] = app; sm.wsums[wid][3] = agg;
    }
    __syncthreads();

    // ---- edge prefix/suffix sums from LDS: 2 lanes per wave, 1 array each ----
    // worker w = 2*wid + lane (w<8); a = {0,1,2,3,5,6,7,8}[w]
    if (lane < 2) {
        const int w = 2 * wid + lane;
        const int a = w < 4 ? w : w + 1;
        const int m = a % 5;                 // 0:P 1:PP 2:G 3:GG
        const bool useG = (m >= 2);
        const bool bwd = (a >= 5);
        const bool opSq = (m & 1);
        const float* buf = useG ? lds_g : lds_p;
        float s = 0.f;
        #pragma unroll
        for (int k = 0; k <= MAXLAG; ++k) {
            sm.edges[a][k] = s;
            if (k < MAXLAG) {
                const int i = bwd ? (LL - 1 - k) : k;
                const float x = buf[pad_idx(i)];
                s += opSq ? x * x : x;
            }
        }
    }

    // ---- g chunk into registers (padded b128 reads) ----
    float gr[CHUNK];
    {
        const int gbase = 20 * tid;
        #pragma unroll
        for (int k = 0; k < CHUNK / 4; ++k) {
            const int v = 32 + 4 * k;
            const int fo = v + 4 * (v / 16);
            const float4 w = *(const float4*)&lds_g[gbase + fo];
            gr[4 * k + 0] = w.x; gr[4 * k + 1] = w.y;
            gr[4 * k + 2] = w.z; gr[4 * k + 3] = w.w;
        }
    }

    // ---- 41 lags: spg only, pure-register inner math, short DPP chains ----
    lag_group<-20, 8>(lds_p, gr, sm, tid);
    lag_group<-12, 8>(lds_p, gr, sm, tid);
    lag_group< -4, 8>(lds_p, gr, sm, tid);
    lag_group<  4, 8>(lds_p, gr, sm, tid);
    lag_group< 12, 8>(lds_p, gr, sm, tid);
    lag_group< 20, 1>(lds_p, gr, sm, tid);
    __syncthreads();

    // ---- per-lag pcc assembly: 41 threads, one lag each ----
    if (tid < NLAGS) {
        const int il = tid;
        const int l = il - MAXLAG;
        const int m = l < 0 ? -l : l;
        const float fn = (float)(LL - m);
        float spg = 0.f;
        #pragma unroll
        for (int r = 0; r < 16; ++r) spg += sm.redPG[r][il];
        const float Sp  = sm.wsums[0][0] + sm.wsums[1][0] + sm.wsums[2][0] + sm.wsums[3][0];
        const float Sg  = sm.wsums[0][1] + sm.wsums[1][1] + sm.wsums[2][1] + sm.wsums[3][1];
        const float Spp = sm.wsums[0][2] + sm.wsums[1][2] + sm.wsums[2][2] + sm.wsums[3][2];
        const float Sgg = sm.wsums[0][3] + sm.wsums[1][3] + sm.wsums[2][3] + sm.wsums[3][3];
        float Spw, Sgw, Sppw, Sggw;
        if (l >= 0) {
            Spw  = Sp  - sm.edges[0][m];
            Sppw = Spp - sm.edges[1][m];
            Sgw  = Sg  - sm.edges[7][m];
            Sggw = Sgg - sm.edges[8][m];
        } else {
            Spw  = Sp  - sm.edges[5][m];
            Sppw = Spp - sm.edges[6][m];
            Sgw  = Sg  - sm.edges[2][m];
            Sggw = Sgg - sm.edges[3][m];
        }
        const float num  = spg - Spw * Sgw / fn;
        const float varp = Sppw - Spw * Spw / fn;
        const float varg = Sggw - Sgw * Sgw / fn;
        const float den2 = fmaxf(varp * varg, 1e-12f);
        sm.pcc_s[il] = num / sqrtf(den2);
    }
    __syncthreads();

    // ---- argmax + softmax penalty (thread 0) ----
    if (tid == 0) {
        float best = sm.pcc_s[0];
        int bi = 0;
        #pragma unroll
        for (int i = 1; i < NLAGS; ++i) {
            if (sm.pcc_s[i] > best) { best = sm.pcc_s[i]; bi = i; }
        }
        float wsum = 0.f, psum = 0.f;
        #pragma unroll
        for (int i = 0; i < NLAGS; ++i) {
            const float w = __expf((sm.pcc_s[i] - best) / TAU);
            wsum += w;
            const int lagi = i - MAXLAG;
            const float lc = (float)(lagi < 0 ? -lagi : lagi) / (float)MAXLAG;
            psum = fmaf(w, lc, psum);
        }
        sm.best_pcc = best;
        sm.zero_pcc = sm.pcc_s[MAXLAG];
        sm.pen = psum / wsum;
        sm.best_il = bi;
    }
    __syncthreads();

    // ---- L1 for the single best lag: masked pass over own chunk ----
    {
        const int bl = sm.best_il - MAXLAG;
        const int c0 = tid * CHUNK;
        float sab = 0.f;
        #pragma unroll
        for (int k = 0; k < CHUNK; ++k) {
            const int pi = c0 + k + bl;                 // p index (g index = c0+k)
            const float p = lds_p[pad_idx(pi)];         // pads are zero; masked below
            const float d = fabsf(p - gr[k]);
            sab += (pi >= 0 && pi < LL) ? d : 0.f;
        }
        sab = row_sum15(sab);
        if ((tid & 15) == 15) sm.l1part[tid >> 4] = sab;
    }
    __syncthreads();

    // ---- final: store per-block scalars (no atomics) ----
    if (tid == 0) {
        const int bl = sm.best_il - MAXLAG;
        const int m = bl < 0 ? -bl : bl;
        float sab = 0.f;
        #pragma unroll
        for (int r = 0; r < 16; ++r) sab += sm.l1part[r];
        const float l1 = sab / (float)(LL - m);
        ws[b] = float4{1.0f - sm.best_pcc, l1, 1.0f - sm.zero_pcc, sm.pen};
    }
}

// ---- stage 2: reduce 512 float4 partials -> 4 output scalars ----
__global__ __launch_bounds__(512) void reduce_kernel(const float4* __restrict__ ws,
                                                     float* __restrict__ out) {
    __shared__ float4 part[8];
    const int tid = threadIdx.x;
    const int wid = tid >> 6;
    const int lane = tid & 63;
    const float4 v = ws[tid];
    const float x = wave_sum63(v.x);
    const float y = wave_sum63(v.y);
    const float z = wave_sum63(v.z);
    const float w = wave_sum63(v.w);
    if (lane == 63) part[wid] = float4{x, y, z, w};
    __syncthreads();
    if (tid == 0) {
        float s0 = 0.f, s1 = 0.f, s2 = 0.f, s3 = 0.f;
        #pragma unroll
        for (int i = 0; i < 8; ++i) {
            s0 += part[i].x; s1 += part[i].y; s2 += part[i].z; s3 += part[i].w;
        }
        const float inv = 1.0f / (float)BB;
        out[0] = s0 * inv;
        out[1] = s1 * inv;
        out[2] = s2 * inv;
        out[3] = s3 * inv;
    }
}

extern "C" void kernel_launch(void* const* d_in, const int* in_sizes, int n_in,
                              void* d_out, int out_size, void* d_ws, size_t ws_size,
                              hipStream_t stream) {
    const float* pred = (const float*)d_in[0];
    const float* gt   = (const float*)d_in[1];
    float* out = (float*)d_out;
    float4* ws = (float4*)d_ws;

    lagloss_kernel<<<BB, 256, 0, stream>>>(pred, gt, ws);
    reduce_kernel<<<1, 512, 0, stream>>>(ws, out);
}

// Round 7
// 15.296 us; speedup vs baseline: 7.3031x; 1.1991x over previous
//
#include <hip/hip_runtime.h>
#include <math.h>

#define BB 512
#define LL 4096
#define MAXLAG 20
#define NLAGS 41
#define TAU 0.05f
#define NT 512
#define CHUNK 8

// Padded LDS layout: element i (i in [-32, 4128)) -> ip = i+32, fi = ip + 4*(ip>>3)
// (4 pad floats per 8 data floats, pitch 12). Thread t owns elements 8t..8t+7:
// pad_idx(8t + x) = 12t + fo(x), fo(x) = (x+32) + 4*((x+32)>>3)  [separable for ALL t].
// Buffer: fi < 6240.

// ---- DPP adds ----
template<int CTRL, int RM, int BM, bool BC>
__device__ __forceinline__ float dpp_add(float x) {
    const int t = __builtin_amdgcn_update_dpp(0, __float_as_int(x), CTRL, RM, BM, BC);
    return x + __int_as_float(t);
}
// full 64-lane sum; result in lane 63
__device__ __forceinline__ float wave_sum63(float x) {
    x = dpp_add<0x111, 0xf, 0xf, true >(x);  // row_shr:1
    x = dpp_add<0x112, 0xf, 0xf, true >(x);  // row_shr:2
    x = dpp_add<0x114, 0xf, 0xf, true >(x);  // row_shr:4
    x = dpp_add<0x118, 0xf, 0xf, true >(x);  // row_shr:8
    x = dpp_add<0x142, 0xa, 0xf, false>(x);  // row_bcast:15
    x = dpp_add<0x143, 0xc, 0xf, false>(x);  // row_bcast:31 -> lane63 total
    return x;
}
// 16-lane row sum; result in lane 15 of each row
__device__ __forceinline__ float row_sum15(float x) {
    x = dpp_add<0x111, 0xf, 0xf, true >(x);
    x = dpp_add<0x112, 0xf, 0xf, true >(x);
    x = dpp_add<0x114, 0xf, 0xf, true >(x);
    x = dpp_add<0x118, 0xf, 0xf, true >(x);
    return x;
}

struct SmemT {
    float redPG[32][NLAGS];       // 32 row-partials per lag
    float edges[10][MAXLAG + 1];  // 0:prefP 1:prefPP 2:prefG 3:prefGG (4 unused)
                                  // 5:sufP  6:sufPP  7:sufG  8:sufGG  (9 unused)
    float wsums[8][4];
    float pcc_s[NLAGS];
    float l1part[32];
    float best_pcc, zero_pcc, pen;
    int best_il;
};

// one lag group: lags L0 .. L0+G-1 (L0 % 4 == 0); computes only spg
template<int L0, int G>
__device__ __forceinline__ void lag_group(const float* __restrict__ lds_p,
                                          const float (&gr)[CHUNK],
                                          SmemT& sm, int tid, bool isTail) {
    constexpr int NW4 = (G + CHUNK + 2) / 4;   // G=8 -> 4 float4, G=1 -> 2
    float pw[NW4 * 4];
    const int pbase = 12 * tid;
    #pragma unroll
    for (int k = 0; k < NW4; ++k) {
        const int x32 = L0 + 4 * k + 32;       // >= 12, mult of 4
        const int fo = x32 + 4 * (x32 >> 3);
        const float4 w = *(const float4*)&lds_p[pbase + fo];
        pw[4 * k + 0] = w.x; pw[4 * k + 1] = w.y;
        pw[4 * k + 2] = w.z; pw[4 * k + 3] = w.w;
    }
    #pragma unroll
    for (int dl = 0; dl < G; ++dl) {
        float s0 = 0.f, s1 = 0.f;
        #pragma unroll
        for (int k = 0; k < CHUNK; k += 2) {
            s0 = fmaf(pw[dl + k],     gr[k],     s0);
            s1 = fmaf(pw[dl + k + 1], gr[k + 1], s1);
        }
        const float spg = row_sum15(s0 + s1);
        if (isTail) sm.redPG[tid >> 4][L0 + MAXLAG + dl] = spg;
    }
}

__global__ __launch_bounds__(NT, 4) void lagloss_kernel(const float* __restrict__ pred,
                                                        const float* __restrict__ gt,
                                                        float4* __restrict__ ws) {
    __shared__ float lds_p[6240];
    __shared__ float lds_g[6240];
    __shared__ SmemT sm;

    const int b = blockIdx.x;
    const int tid = threadIdx.x;
    const int wid = tid >> 6;
    const int lane = tid & 63;
    const float* __restrict__ prow = pred + (size_t)b * LL;
    const float* __restrict__ grow = gt + (size_t)b * LL;

    // ---- zero the pads: ip in [0,32) and [4128,4160) for both buffers ----
    if (tid < 32) {
        const int m = tid & 7;
        const int ip = ((tid & 8) ? 4128 : 0) + 4 * m;
        const int fi = ip + 4 * (ip >> 3);
        float* buf = (tid < 16) ? lds_p : lds_g;
        *(float4*)&buf[fi] = float4{0.f, 0.f, 0.f, 0.f};
    }

    // ---- stage rows into padded LDS (coalesced float4) + full-row sums ----
    const int wb = 4 * tid + 32 + 4 * ((tid + 8) >> 1);
    float ap = 0.f, ag = 0.f, app = 0.f, agg = 0.f;
    #pragma unroll
    for (int it = 0; it < 2; ++it) {
        const int j = tid + NT * it;
        const float4 p4 = ((const float4*)prow)[j];
        const float4 g4 = ((const float4*)grow)[j];
        *(float4*)&lds_p[wb + 3072 * it] = p4;
        *(float4*)&lds_g[wb + 3072 * it] = g4;
        ap += p4.x + p4.y + p4.z + p4.w;
        ag += g4.x + g4.y + g4.z + g4.w;
        app = fmaf(p4.x, p4.x, fmaf(p4.y, p4.y, fmaf(p4.z, p4.z, fmaf(p4.w, p4.w, app))));
        agg = fmaf(g4.x, g4.x, fmaf(g4.y, g4.y, fmaf(g4.z, g4.z, fmaf(g4.w, g4.w, agg))));
    }
    ap = wave_sum63(ap); ag = wave_sum63(ag);
    app = wave_sum63(app); agg = wave_sum63(agg);
    if (lane == 63) {
        sm.wsums[wid][0] = ap; sm.wsums[wid][1] = ag;
        sm.wsums[wid][2] = app; sm.wsums[wid][3] = agg;
    }
    __syncthreads();

    // ---- edge prefix/suffix sums: wave 0 lanes 0..7, one array each ----
    if (wid == 0 && lane < 8) {
        const int a = (lane < 4) ? lane : lane + 1;   // {0,1,2,3,5,6,7,8}
        const int m = a % 5;
        const bool useG = (m >= 2);
        const bool bwd = (a >= 5);
        const bool opSq = (m & 1);
        const float* buf = useG ? lds_g : lds_p;
        float s = 0.f;
        #pragma unroll
        for (int k = 0; k <= MAXLAG; ++k) {
            sm.edges[a][k] = s;
            if (k < MAXLAG) {
                const int i = bwd ? (LL - 1 - k) : k;
                const int ip = i + 32;
                const float x = buf[ip + 4 * (ip >> 3)];
                s += opSq ? x * x : x;
            }
        }
    }

    // ---- g chunk into registers ----
    float gr[CHUNK];
    {
        const int gbase = 12 * tid;
        const float4 a = *(const float4*)&lds_g[gbase + 48];  // fo(0)
        const float4 c = *(const float4*)&lds_g[gbase + 52];  // fo(4)
        gr[0] = a.x; gr[1] = a.y; gr[2] = a.z; gr[3] = a.w;
        gr[4] = c.x; gr[5] = c.y; gr[6] = c.z; gr[7] = c.w;
    }
    const bool isTail = ((tid & 15) == 15);

    // ---- 41 lags: spg only, pure-register inner math, short DPP chains ----
    lag_group<-20, 8>(lds_p, gr, sm, tid, isTail);
    lag_group<-12, 8>(lds_p, gr, sm, tid, isTail);
    lag_group< -4, 8>(lds_p, gr, sm, tid, isTail);
    lag_group<  4, 8>(lds_p, gr, sm, tid, isTail);
    lag_group< 12, 8>(lds_p, gr, sm, tid, isTail);
    lag_group< 20, 1>(lds_p, gr, sm, tid, isTail);
    __syncthreads();

    // ---- per-lag pcc assembly: 41 threads (wave 0), one lag each ----
    if (tid < NLAGS) {
        const int il = tid;
        const int l = il - MAXLAG;
        const int m = l < 0 ? -l : l;
        const float fn = (float)(LL - m);
        float spg = 0.f;
        #pragma unroll
        for (int r = 0; r < 32; ++r) spg += sm.redPG[r][il];
        float Sp = 0.f, Sg = 0.f, Spp = 0.f, Sgg = 0.f;
        #pragma unroll
        for (int w = 0; w < 8; ++w) {
            Sp += sm.wsums[w][0]; Sg += sm.wsums[w][1];
            Spp += sm.wsums[w][2]; Sgg += sm.wsums[w][3];
        }
        float Spw, Sgw, Sppw, Sggw;
        if (l >= 0) {
            Spw  = Sp  - sm.edges[0][m];
            Sppw = Spp - sm.edges[1][m];
            Sgw  = Sg  - sm.edges[7][m];
            Sggw = Sgg - sm.edges[8][m];
        } else {
            Spw  = Sp  - sm.edges[5][m];
            Sppw = Spp - sm.edges[6][m];
            Sgw  = Sg  - sm.edges[2][m];
            Sggw = Sgg - sm.edges[3][m];
        }
        const float num  = spg - Spw * Sgw / fn;
        const float varp = Sppw - Spw * Spw / fn;
        const float varg = Sggw - Sgw * Sgw / fn;
        const float den2 = fmaxf(varp * varg, 1e-12f);
        sm.pcc_s[il] = num / sqrtf(den2);
    }
    __syncthreads();

    // ---- argmax + softmax penalty: wave 0, lane-parallel ----
    if (wid == 0) {
        const float v = (lane < NLAGS) ? sm.pcc_s[lane] : -3.0f;
        float bv = v;
        int bi = lane;
        #pragma unroll
        for (int d = 32; d; d >>= 1) {
            const float ov = __shfl_xor(bv, d, 64);
            const int oi = __shfl_xor(bi, d, 64);
            if (ov > bv || (ov == bv && oi < bi)) { bv = ov; bi = oi; }
        }
        const float e = (lane < NLAGS) ? __expf((v - bv) * (1.0f / TAU)) : 0.0f;
        const float lc = (lane < NLAGS) ? fabsf((float)(lane - MAXLAG)) * (1.0f / MAXLAG) : 0.0f;
        float wsum = e, psum = e * lc;
        #pragma unroll
        for (int d = 32; d; d >>= 1) {
            wsum += __shfl_xor(wsum, d, 64);
            psum += __shfl_xor(psum, d, 64);
        }
        if (lane == 0) {
            sm.best_pcc = bv;
            sm.best_il = bi;
            sm.zero_pcc = sm.pcc_s[MAXLAG];
            sm.pen = psum / wsum;
        }
    }
    __syncthreads();

    // ---- L1 for the single best lag: masked pass over own chunk ----
    {
        const int bl = sm.best_il - MAXLAG;
        const int c0 = tid * CHUNK;
        float sab = 0.f;
        #pragma unroll
        for (int k = 0; k < CHUNK; ++k) {
            const int pi = c0 + k + bl;
            const int ip = pi + 32;
            const float p = lds_p[ip + 4 * (ip >> 3)];  // pads are zero
            const float d = fabsf(p - gr[k]);
            sab += (pi >= 0 && pi < LL) ? d : 0.f;
        }
        sab = row_sum15(sab);
        if (isTail) sm.l1part[tid >> 4] = sab;
    }
    __syncthreads();

    // ---- final: store per-block scalars (no atomics) ----
    if (tid == 0) {
        const int bl = sm.best_il - MAXLAG;
        const int m = bl < 0 ? -bl : bl;
        float sab = 0.f;
        #pragma unroll
        for (int r = 0; r < 32; ++r) sab += sm.l1part[r];
        const float l1 = sab / (float)(LL - m);
        ws[b] = float4{1.0f - sm.best_pcc, l1, 1.0f - sm.zero_pcc, sm.pen};
    }
}

// ---- stage 2: reduce 512 float4 partials -> 4 output scalars ----
__global__ __launch_bounds__(512) void reduce_kernel(const float4* __restrict__ ws,
                                                     float* __restrict__ out) {
    __shared__ float4 part[8];
    const int tid = threadIdx.x;
    const int wid = tid >> 6;
    const int lane = tid & 63;
    const float4 v = ws[tid];
    const float x = wave_sum63(v.x);
    const float y = wave_sum63(v.y);
    const float z = wave_sum63(v.z);
    const float w = wave_sum63(v.w);
    if (lane == 63) part[wid] = float4{x, y, z, w};
    __syncthreads();
    if (tid == 0) {
        float s0 = 0.f, s1 = 0.f, s2 = 0.f, s3 = 0.f;
        #pragma unroll
        for (int i = 0; i < 8; ++i) {
            s0 += part[i].x; s1 += part[i].y; s2 += part[i].z; s3 += part[i].w;
        }
        const float inv = 1.0f / (float)BB;
        out[0] = s0 * inv;
        out[1] = s1 * inv;
        out[2] = s2 * inv;
        out[3] = s3 * inv;
    }
}

extern "C" void kernel_launch(void* const* d_in, const int* in_sizes, int n_in,
                              void* d_out, int out_size, void* d_ws, size_t ws_size,
                              hipStream_t stream) {
    const float* pred = (const float*)d_in[0];
    const float* gt   = (const float*)d_in[1];
    float* out = (float*)d_out;
    float4* ws = (float4*)d_ws;

    lagloss_kernel<<<BB, NT, 0, stream>>>(pred, gt, ws);
    reduce_kernel<<<1, 512, 0, stream>>>(ws, out);
}